// Round 1
// baseline (733.527 us; speedup 1.0000x reference)
//
#include <hip/hip_runtime.h>
#include <math.h>

#define BATCH   64
#define NROWS   1024
#define DIM     768
#define NSLOTS  16
#define NWAVES  16
#define BLOCKT  1024

// One block per batch element. 16 waves x 64 lanes.
// Wave w owns rows [w*64, w*64+64). Lane l owns columns {c*256 + l*4 .. +3 : c=0,1,2}.

__global__ __launch_bounds__(BLOCKT, 1)
void greedy_feature_init_kernel(const float* __restrict__ feat,
                                float* __restrict__ out) {
    const int b    = blockIdx.x;
    const int tid  = threadIdx.x;
    const int wave = tid >> 6;
    const int lane = tid & 63;

    __shared__ float s_mask[NROWS];
    __shared__ float s_sal[NROWS];
    __shared__ float s_rsal[NROWS];
    __shared__ __align__(16) float s_sel[DIM];
    __shared__ __align__(16) float s_red[NWAVES * DIM];   // 48 KiB
    __shared__ float s_wsum[NWAVES];
    __shared__ float s_argv[NWAVES];
    __shared__ int   s_argi[NWAVES];
    __shared__ int   s_idx;

    const float* fb = feat + (size_t)b * NROWS * DIM;

    // ---- Phase 0: saliency = ||f[n,:]||, mask = 1 ----
    {
        const int r0 = wave * 64;
        for (int r = r0; r < r0 + 64; ++r) {
            const float4* rp = (const float4*)(fb + (size_t)r * DIM);
            float4 v0 = rp[lane];
            float4 v1 = rp[lane + 64];
            float4 v2 = rp[lane + 128];
            float ss = v0.x*v0.x + v0.y*v0.y + v0.z*v0.z + v0.w*v0.w
                     + v1.x*v1.x + v1.y*v1.y + v1.z*v1.z + v1.w*v1.w
                     + v2.x*v2.x + v2.y*v2.y + v2.z*v2.z + v2.w*v2.w;
            #pragma unroll
            for (int off = 32; off; off >>= 1) ss += __shfl_xor(ss, off);
            if (lane == 0) {
                float nrm = sqrtf(ss);
                s_sal[r]  = nrm;
                s_rsal[r] = 1.0f / fmaxf(nrm, 1e-12f);
                s_mask[r] = 1.0f;
            }
        }
    }
    __syncthreads();

    // ---- Slot loop ----
    for (int t = 0; t < NSLOTS; ++t) {
        // (a) argmax over masked saliency (ties -> lowest index, like jnp.argmax)
        {
            int   n  = tid;                 // 1024 threads <-> 1024 rows
            float bv = s_sal[n] * s_mask[n];
            int   bi = n;
            #pragma unroll
            for (int off = 32; off; off >>= 1) {
                float ov = __shfl_xor(bv, off);
                int   oi = __shfl_xor(bi, off);
                if (ov > bv || (ov == bv && oi < bi)) { bv = ov; bi = oi; }
            }
            if (lane == 0) { s_argv[wave] = bv; s_argi[wave] = bi; }
        }
        __syncthreads();
        if (tid == 0) {
            float best  = s_argv[0];
            int   besti = s_argi[0];
            #pragma unroll
            for (int w = 1; w < NWAVES; ++w) {
                float v = s_argv[w]; int i = s_argi[w];
                if (v > best || (v == best && i < besti)) { best = v; besti = i; }
            }
            s_idx = besti;
        }
        __syncthreads();
        const int idx = s_idx;

        // (b) selected normalized row -> s_sel  (norm(selected) == saliency[idx])
        if (tid < DIM) {
            float rn = 1.0f / fmaxf(s_sal[idx], 1e-12f);
            s_sel[tid] = fb[(size_t)idx * DIM + tid] * rn;
        }
        __syncthreads();

        // preload sel fragments into registers (lane-owned columns)
        const float4* selp = (const float4*)s_sel;
        float4 sel0 = selp[lane];
        float4 sel1 = selp[lane + 64];
        float4 sel2 = selp[lane + 128];

        // (c) fused pass: sim -> weight -> accumulate w*f, update mask
        float4 acc0 = {0.f,0.f,0.f,0.f};
        float4 acc1 = {0.f,0.f,0.f,0.f};
        float4 acc2 = {0.f,0.f,0.f,0.f};
        float  wsum = 0.f;

        const int r0 = wave * 64;
        for (int r = r0; r < r0 + 64; ++r) {
            const float4* rp = (const float4*)(fb + (size_t)r * DIM);
            float4 v0 = rp[lane];
            float4 v1 = rp[lane + 64];
            float4 v2 = rp[lane + 128];

            float dot = 0.f;
            dot = fmaf(v0.x, sel0.x, dot); dot = fmaf(v0.y, sel0.y, dot);
            dot = fmaf(v0.z, sel0.z, dot); dot = fmaf(v0.w, sel0.w, dot);
            dot = fmaf(v1.x, sel1.x, dot); dot = fmaf(v1.y, sel1.y, dot);
            dot = fmaf(v1.z, sel1.z, dot); dot = fmaf(v1.w, sel1.w, dot);
            dot = fmaf(v2.x, sel2.x, dot); dot = fmaf(v2.y, sel2.y, dot);
            dot = fmaf(v2.z, sel2.z, dot); dot = fmaf(v2.w, sel2.w, dot);
            #pragma unroll
            for (int off = 32; off; off >>= 1) dot += __shfl_xor(dot, off);

            float sim = dot * s_rsal[r];
            float m   = s_mask[r];
            float wr  = (sim > 0.5f) ? (sim * m) : 0.f;   // sim*m >= 0 here

            if (lane == 0) {
                float c = fminf(fmaxf(sim, 0.f), 1.f);
                s_mask[r] = m * (1.0f - c);
            }

            wsum += wr;
            acc0.x = fmaf(wr, v0.x, acc0.x); acc0.y = fmaf(wr, v0.y, acc0.y);
            acc0.z = fmaf(wr, v0.z, acc0.z); acc0.w = fmaf(wr, v0.w, acc0.w);
            acc1.x = fmaf(wr, v1.x, acc1.x); acc1.y = fmaf(wr, v1.y, acc1.y);
            acc1.z = fmaf(wr, v1.z, acc1.z); acc1.w = fmaf(wr, v1.w, acc1.w);
            acc2.x = fmaf(wr, v2.x, acc2.x); acc2.y = fmaf(wr, v2.y, acc2.y);
            acc2.z = fmaf(wr, v2.z, acc2.z); acc2.w = fmaf(wr, v2.w, acc2.w);
        }

        // cross-wave reduction of slot numerator + weight sum
        {
            float4* red = (float4*)(s_red + wave * DIM);
            red[lane]       = acc0;
            red[lane + 64]  = acc1;
            red[lane + 128] = acc2;
            if (lane == 0) s_wsum[wave] = wsum;
        }
        __syncthreads();

        if (tid < DIM) {
            float s = 0.f;
            #pragma unroll
            for (int w = 0; w < NWAVES; ++w) s += s_red[w * DIM + tid];
            float den = 0.f;
            #pragma unroll
            for (int w = 0; w < NWAVES; ++w) den += s_wsum[w];
            out[((size_t)b * NSLOTS + t) * DIM + tid] = s / (den + 1e-8f);
        }
        __syncthreads();   // protect s_red/s_wsum before next iteration
    }
}

extern "C" void kernel_launch(void* const* d_in, const int* in_sizes, int n_in,
                              void* d_out, int out_size, void* d_ws, size_t ws_size,
                              hipStream_t stream) {
    const float* feat = (const float*)d_in[0];
    float* out = (float*)d_out;
    (void)in_sizes; (void)n_in; (void)d_ws; (void)ws_size; (void)out_size;
    greedy_feature_init_kernel<<<BATCH, BLOCKT, 0, stream>>>(feat, out);
}

// Round 2
// 608.393 us; speedup vs baseline: 1.2057x; 1.2057x over previous
//
#include <hip/hip_runtime.h>
#include <math.h>

#define B_      64
#define N_      1024
#define D_      768
#define T_      16
#define SLABS   32          // blocks per batch in pass kernels
#define ROWS_PB 32          // rows per block (N_/SLABS)
#define ROWS_PW 8           // rows per wave (4 waves/block)
#define THR     256

__device__ __forceinline__ float wave_sum(float v) {
    #pragma unroll
    for (int off = 32; off; off >>= 1) v += __shfl_xor(v, off);
    return v;
}

// ---------------- pass 0: saliency + initial argmax partials ----------------
__global__ __launch_bounds__(THR)
void k_sal(const float* __restrict__ feat, float* __restrict__ sal,
           float* __restrict__ rsal, float* __restrict__ mask,
           float* __restrict__ argv, float* __restrict__ args,
           int* __restrict__ argi) {
    const int blk = blockIdx.x, b = blk >> 5, g = blk & 31;
    const int tid = threadIdx.x, wave = tid >> 6, lane = tid & 63;
    __shared__ float s_sal[ROWS_PB];

    const float* fb = feat + ((size_t)b * N_ + (size_t)g * ROWS_PB) * D_;
    const int r0 = wave * ROWS_PW;
    #pragma unroll 2
    for (int r = r0; r < r0 + ROWS_PW; ++r) {
        const float4* rp = (const float4*)(fb + (size_t)r * D_);
        float4 v0 = rp[lane], v1 = rp[lane + 64], v2 = rp[lane + 128];
        float ss = v0.x*v0.x + v0.y*v0.y + v0.z*v0.z + v0.w*v0.w
                 + v1.x*v1.x + v1.y*v1.y + v1.z*v1.z + v1.w*v1.w
                 + v2.x*v2.x + v2.y*v2.y + v2.z*v2.z + v2.w*v2.w;
        ss = wave_sum(ss);
        if (lane == 0) s_sal[r] = sqrtf(ss);
    }
    __syncthreads();

    const int rg = b * N_ + g * ROWS_PB;
    if (tid < ROWS_PB) {
        float n = s_sal[tid];
        sal[rg + tid]  = n;
        rsal[rg + tid] = 1.0f / fmaxf(n, 1e-12f);
        mask[rg + tid] = 1.0f;
    }
    if (wave == 0) {
        float v  = (lane < ROWS_PB) ? s_sal[lane] : -INFINITY;
        float sv = v;
        int   i  = (lane < ROWS_PB) ? (g * ROWS_PB + lane) : 0x7fffffff;
        #pragma unroll
        for (int off = 32; off; off >>= 1) {
            float ov = __shfl_xor(v, off);
            float osv = __shfl_xor(sv, off);
            int   oi = __shfl_xor(i, off);
            if (ov > v || (ov == v && oi < i)) { v = ov; sv = osv; i = oi; }
        }
        if (lane == 0) { argv[b*SLABS+g] = v; args[b*SLABS+g] = sv; argi[b*SLABS+g] = i; }
    }
}

// ---------------- per-slot main pass ----------------
// reads sel (normalized selected row), computes sim/weights for its 32 rows,
// updates mask, writes partial numerator + wsum, and next-slot argmax partial.
__global__ __launch_bounds__(THR)
void k_fused(const float* __restrict__ feat, const float* __restrict__ sel,
             const float* __restrict__ sal, const float* __restrict__ rsal,
             float* __restrict__ mask, float* __restrict__ num,
             float* __restrict__ wsum, float* __restrict__ argv,
             float* __restrict__ args, int* __restrict__ argi) {
    const int blk = blockIdx.x, b = blk >> 5, g = blk & 31;
    const int tid = threadIdx.x, wave = tid >> 6, lane = tid & 63;

    __shared__ __align__(16) float s_red[4 * D_];   // 12 KiB
    __shared__ float s_wsum[4];
    __shared__ float s_msal[ROWS_PB];
    __shared__ float s_salL[ROWS_PB];

    const float* fb = feat + ((size_t)b * N_ + (size_t)g * ROWS_PB) * D_;
    const float4* selp = (const float4*)(sel + (size_t)b * D_);
    float4 sel0 = selp[lane], sel1 = selp[lane + 64], sel2 = selp[lane + 128];

    float4 acc0 = {0.f,0.f,0.f,0.f};
    float4 acc1 = {0.f,0.f,0.f,0.f};
    float4 acc2 = {0.f,0.f,0.f,0.f};
    float  wsl  = 0.f;

    const int rbase = b * N_ + g * ROWS_PB;
    const int r0 = wave * ROWS_PW;
    #pragma unroll 2
    for (int r = r0; r < r0 + ROWS_PW; ++r) {
        const float4* rp = (const float4*)(fb + (size_t)r * D_);
        float4 v0 = rp[lane], v1 = rp[lane + 64], v2 = rp[lane + 128];

        float dot = 0.f;
        dot = fmaf(v0.x, sel0.x, dot); dot = fmaf(v0.y, sel0.y, dot);
        dot = fmaf(v0.z, sel0.z, dot); dot = fmaf(v0.w, sel0.w, dot);
        dot = fmaf(v1.x, sel1.x, dot); dot = fmaf(v1.y, sel1.y, dot);
        dot = fmaf(v1.z, sel1.z, dot); dot = fmaf(v1.w, sel1.w, dot);
        dot = fmaf(v2.x, sel2.x, dot); dot = fmaf(v2.y, sel2.y, dot);
        dot = fmaf(v2.z, sel2.z, dot); dot = fmaf(v2.w, sel2.w, dot);
        dot = wave_sum(dot);

        float rs  = rsal[rbase + r];
        float sv  = sal[rbase + r];
        float m   = mask[rbase + r];
        float sim = dot * rs;
        float wr  = (sim > 0.5f) ? (sim * m) : 0.f;   // sim*m >= 0 when sim>0.5
        float nm  = m * (1.0f - fminf(fmaxf(sim, 0.f), 1.f));

        if (lane == 0) {
            mask[rbase + r] = nm;
            s_msal[r] = sv * nm;
            s_salL[r] = sv;
        }

        wsl += wr;
        acc0.x = fmaf(wr, v0.x, acc0.x); acc0.y = fmaf(wr, v0.y, acc0.y);
        acc0.z = fmaf(wr, v0.z, acc0.z); acc0.w = fmaf(wr, v0.w, acc0.w);
        acc1.x = fmaf(wr, v1.x, acc1.x); acc1.y = fmaf(wr, v1.y, acc1.y);
        acc1.z = fmaf(wr, v1.z, acc1.z); acc1.w = fmaf(wr, v1.w, acc1.w);
        acc2.x = fmaf(wr, v2.x, acc2.x); acc2.y = fmaf(wr, v2.y, acc2.y);
        acc2.z = fmaf(wr, v2.z, acc2.z); acc2.w = fmaf(wr, v2.w, acc2.w);
    }

    {
        float4* red = (float4*)(s_red + wave * D_);
        red[lane]       = acc0;
        red[lane + 64]  = acc1;
        red[lane + 128] = acc2;
        if (lane == 0) s_wsum[wave] = wsl;
    }
    __syncthreads();

    for (int c = tid; c < D_; c += THR) {
        float s = s_red[c] + s_red[D_ + c] + s_red[2*D_ + c] + s_red[3*D_ + c];
        num[((size_t)b * SLABS + g) * D_ + c] = s;
    }
    if (tid == 0)
        wsum[b*SLABS+g] = s_wsum[0] + s_wsum[1] + s_wsum[2] + s_wsum[3];

    if (wave == 0) {
        float v  = (lane < ROWS_PB) ? s_msal[lane] : -INFINITY;
        float sv = (lane < ROWS_PB) ? s_salL[lane] : 0.f;
        int   i  = (lane < ROWS_PB) ? (g * ROWS_PB + lane) : 0x7fffffff;
        #pragma unroll
        for (int off = 32; off; off >>= 1) {
            float ov = __shfl_xor(v, off);
            float osv = __shfl_xor(sv, off);
            int   oi = __shfl_xor(i, off);
            if (ov > v || (ov == v && oi < i)) { v = ov; sv = osv; i = oi; }
        }
        if (lane == 0) { argv[b*SLABS+g] = v; args[b*SLABS+g] = sv; argi[b*SLABS+g] = i; }
    }
}

// ---------------- per-slot reduce: write out[t], compute next sel ----------------
__global__ __launch_bounds__(192)
void k_out(const float* __restrict__ feat, const float* __restrict__ num,
           const float* __restrict__ wsumA, const float* __restrict__ argv,
           const float* __restrict__ args, const int* __restrict__ argi,
           float* __restrict__ sel, float* __restrict__ out, int t) {
    const int b = blockIdx.x >> 2, q = blockIdx.x & 3;
    const int tid = threadIdx.x, lane = tid & 63;

    __shared__ float s_rsel;
    __shared__ int   s_idx;
    __shared__ float s_ws;

    if (tid < 64) {
        float v  = (lane < SLABS) ? argv[b*SLABS + lane] : -INFINITY;
        float sv = (lane < SLABS) ? args[b*SLABS + lane] : 0.f;
        int   i  = (lane < SLABS) ? argi[b*SLABS + lane] : 0x7fffffff;
        float w  = (lane < SLABS) ? wsumA[b*SLABS + lane] : 0.f;
        #pragma unroll
        for (int off = 32; off; off >>= 1) {
            float ov = __shfl_xor(v, off);
            float osv = __shfl_xor(sv, off);
            int   oi = __shfl_xor(i, off);
            w += __shfl_xor(w, off);
            if (ov > v || (ov == v && oi < i)) { v = ov; sv = osv; i = oi; }
        }
        if (lane == 0) {
            s_idx  = i;
            s_rsel = 1.0f / fmaxf(sv, 1e-12f);
            s_ws   = w;
        }
    }
    __syncthreads();

    const int c = q * 192 + tid;
    if (t >= 0) {
        float s = 0.f;
        #pragma unroll 8
        for (int g = 0; g < SLABS; ++g)
            s += num[((size_t)b * SLABS + g) * D_ + c];
        out[((size_t)b * T_ + t) * D_ + c] = s / (s_ws + 1e-8f);
    }
    sel[(size_t)b * D_ + c] = feat[((size_t)b * N_ + s_idx) * D_ + c] * s_rsel;
}

// ---------------- fallback: round-1 single-kernel (if ws too small) ----------------
__global__ __launch_bounds__(1024, 1)
void greedy_mono(const float* __restrict__ feat, float* __restrict__ out) {
    const int b = blockIdx.x, tid = threadIdx.x, wave = tid >> 6, lane = tid & 63;
    __shared__ float s_mask[N_], s_sal[N_], s_rsal[N_];
    __shared__ __align__(16) float s_sel[D_];
    __shared__ __align__(16) float s_red[16 * D_];
    __shared__ float s_wsum[16], s_argv[16];
    __shared__ int s_argi[16], s_idx;
    const float* fb = feat + (size_t)b * N_ * D_;
    {
        const int r0 = wave * 64;
        for (int r = r0; r < r0 + 64; ++r) {
            const float4* rp = (const float4*)(fb + (size_t)r * D_);
            float4 v0 = rp[lane], v1 = rp[lane+64], v2 = rp[lane+128];
            float ss = v0.x*v0.x+v0.y*v0.y+v0.z*v0.z+v0.w*v0.w
                     + v1.x*v1.x+v1.y*v1.y+v1.z*v1.z+v1.w*v1.w
                     + v2.x*v2.x+v2.y*v2.y+v2.z*v2.z+v2.w*v2.w;
            ss = wave_sum(ss);
            if (lane == 0) { float n = sqrtf(ss); s_sal[r]=n; s_rsal[r]=1.f/fmaxf(n,1e-12f); s_mask[r]=1.f; }
        }
    }
    __syncthreads();
    for (int t = 0; t < T_; ++t) {
        {
            float bv = s_sal[tid] * s_mask[tid]; int bi = tid;
            #pragma unroll
            for (int off = 32; off; off >>= 1) {
                float ov = __shfl_xor(bv, off); int oi = __shfl_xor(bi, off);
                if (ov > bv || (ov == bv && oi < bi)) { bv = ov; bi = oi; }
            }
            if (lane == 0) { s_argv[wave] = bv; s_argi[wave] = bi; }
        }
        __syncthreads();
        if (tid == 0) {
            float best = s_argv[0]; int besti = s_argi[0];
            #pragma unroll
            for (int w = 1; w < 16; ++w) {
                float v = s_argv[w]; int i = s_argi[w];
                if (v > best || (v == best && i < besti)) { best = v; besti = i; }
            }
            s_idx = besti;
        }
        __syncthreads();
        const int idx = s_idx;
        if (tid < D_) s_sel[tid] = fb[(size_t)idx*D_+tid] * (1.f/fmaxf(s_sal[idx],1e-12f));
        __syncthreads();
        const float4* selp = (const float4*)s_sel;
        float4 sel0 = selp[lane], sel1 = selp[lane+64], sel2 = selp[lane+128];
        float4 a0={0,0,0,0}, a1={0,0,0,0}, a2={0,0,0,0}; float wsl=0.f;
        const int r0 = wave * 64;
        for (int r = r0; r < r0 + 64; ++r) {
            const float4* rp = (const float4*)(fb + (size_t)r * D_);
            float4 v0 = rp[lane], v1 = rp[lane+64], v2 = rp[lane+128];
            float dot = 0.f;
            dot=fmaf(v0.x,sel0.x,dot); dot=fmaf(v0.y,sel0.y,dot); dot=fmaf(v0.z,sel0.z,dot); dot=fmaf(v0.w,sel0.w,dot);
            dot=fmaf(v1.x,sel1.x,dot); dot=fmaf(v1.y,sel1.y,dot); dot=fmaf(v1.z,sel1.z,dot); dot=fmaf(v1.w,sel1.w,dot);
            dot=fmaf(v2.x,sel2.x,dot); dot=fmaf(v2.y,sel2.y,dot); dot=fmaf(v2.z,sel2.z,dot); dot=fmaf(v2.w,sel2.w,dot);
            dot = wave_sum(dot);
            float sim = dot * s_rsal[r], m = s_mask[r];
            float wr = (sim > 0.5f) ? (sim * m) : 0.f;
            if (lane == 0) s_mask[r] = m * (1.f - fminf(fmaxf(sim,0.f),1.f));
            wsl += wr;
            a0.x=fmaf(wr,v0.x,a0.x); a0.y=fmaf(wr,v0.y,a0.y); a0.z=fmaf(wr,v0.z,a0.z); a0.w=fmaf(wr,v0.w,a0.w);
            a1.x=fmaf(wr,v1.x,a1.x); a1.y=fmaf(wr,v1.y,a1.y); a1.z=fmaf(wr,v1.z,a1.z); a1.w=fmaf(wr,v1.w,a1.w);
            a2.x=fmaf(wr,v2.x,a2.x); a2.y=fmaf(wr,v2.y,a2.y); a2.z=fmaf(wr,v2.z,a2.z); a2.w=fmaf(wr,v2.w,a2.w);
        }
        {
            float4* red = (float4*)(s_red + wave * D_);
            red[lane]=a0; red[lane+64]=a1; red[lane+128]=a2;
            if (lane == 0) s_wsum[wave] = wsl;
        }
        __syncthreads();
        if (tid < D_) {
            float s = 0.f, den = 0.f;
            #pragma unroll
            for (int w = 0; w < 16; ++w) { s += s_red[w*D_+tid]; den += s_wsum[w]; }
            out[((size_t)b*T_+t)*D_+tid] = s / (den + 1e-8f);
        }
        __syncthreads();
    }
}

extern "C" void kernel_launch(void* const* d_in, const int* in_sizes, int n_in,
                              void* d_out, int out_size, void* d_ws, size_t ws_size,
                              hipStream_t stream) {
    const float* feat = (const float*)d_in[0];
    float* out = (float*)d_out;
    (void)in_sizes; (void)n_in; (void)out_size;

    // workspace carving (floats)
    const size_t n_sal  = (size_t)B_ * N_;
    const size_t n_arg  = (size_t)B_ * SLABS;
    const size_t n_sel  = (size_t)B_ * D_;
    const size_t n_num  = (size_t)B_ * SLABS * D_;
    const size_t need   = (3*n_sal + 4*n_arg + n_sel + n_num) * sizeof(float);

    if (ws_size < need) {
        greedy_mono<<<B_, 1024, 0, stream>>>(feat, out);
        return;
    }

    float* p = (float*)d_ws;
    float* sal  = p;            p += n_sal;
    float* rsal = p;            p += n_sal;
    float* mask = p;            p += n_sal;
    float* argv = p;            p += n_arg;
    float* args = p;            p += n_arg;
    int*   argi = (int*)p;      p += n_arg;
    float* wsum = p;            p += n_arg;
    float* sel  = p;            p += n_sel;
    float* num  = p;            p += n_num;

    k_sal<<<B_*SLABS, THR, 0, stream>>>(feat, sal, rsal, mask, argv, args, argi);
    k_out<<<B_*4, 192, 0, stream>>>(feat, num, wsum, argv, args, argi, sel, out, -1);
    for (int t = 0; t < T_; ++t) {
        k_fused<<<B_*SLABS, THR, 0, stream>>>(feat, sel, sal, rsal, mask,
                                              num, wsum, argv, args, argi);
        k_out<<<B_*4, 192, 0, stream>>>(feat, num, wsum, argv, args, argi, sel, out, t);
    }
}